// Round 11
// baseline (48.974 us; speedup 1.0000x reference)
//
#include <hip/hip_runtime.h>
#include <math.h>

#define MAX_T 2048
#define SEG_P 4   // segments per pool block (measured optimum: {1:40.6, 2:37.5, 4:35.3, 8:~39} µs)

// ---------------- Kernel 1: score = sigmoid(feat . W + b) ----------------
// One wave (64 lanes) per (b,t) row. float4 coalesced loads.
__global__ void score_kernel(const float* __restrict__ feat,
                             const float* __restrict__ W,
                             const float* __restrict__ bias,
                             float* __restrict__ score,
                             int nrows, int D) {
  int row = blockIdx.x * 4 + (threadIdx.x >> 6);
  int lane = threadIdx.x & 63;
  if (row >= nrows) return;
  const float4* f4 = (const float4*)(feat + (size_t)row * D);
  const float4* w4 = (const float4*)W;
  float acc = 0.f;
  int n4 = D >> 2;
  for (int idx = lane; idx < n4; idx += 64) {
    float4 a = f4[idx];
    float4 w = w4[idx];
    acc += a.x * w.x + a.y * w.y + a.z * w.z + a.w * w.w;
  }
#pragma unroll
  for (int off = 32; off > 0; off >>= 1) acc += __shfl_xor(acc, off, 64);
  if (lane == 0) {
    float x = acc + bias[0];
    score[row] = 1.f / (1.f + expf(-x));
  }
}

// ---------------- Kernel 2: fused seg + pool ----------------
// One 128-thread block per SEG_P consecutive segments of one batch.
// Each block redundantly recomputes its batch's valley table in LDS
// (score row is L2/L3-resident after kernel 1; the scan is cheap and
// fully parallel across blocks), then runs the proven R5 rolling-atom
// pool body reading score and vi from LDS.
// Atom j := [vi[j-1], vi[j]) with vi[-1]:=0. Segment k = atom k U atom k+1
// (k<hn-1); segment hn-1 = atom hn-1 (vi[hn-1]==hl-1 forced).
__global__ __launch_bounds__(128) void segpool_kernel(
    const float* __restrict__ feat, const float* __restrict__ score,
    const int* __restrict__ hlens, float* __restrict__ out,
    float* __restrict__ hn_out, int T, int D, int M, int ngrp) {
  int gid = blockIdx.x;
  int tid = threadIdx.x;
  int b = gid / ngrp;
  int g = gid - b * ngrp;
  int k0 = g * SEG_P;

  __shared__ float s[MAX_T];
  __shared__ unsigned short vi[MAX_T];
  __shared__ int wsum[2];

  const float* sr = score + (size_t)b * T;
  int hl = hlens[b];

  for (int t = tid; t < T; t += 128) s[t] = sr[t];
  __syncthreads();

  // per-thread chunk valley counts (flag recomputed on the fly)
  int C = (T + 127) / 128;              // 16 for T=2000
  int lo = tid * C;
  int hi = lo + C; if (hi > T) hi = T; if (lo > T) lo = T;
  auto flag = [&](int t) -> bool {
    if (t >= hl) return false;
    if (t == 0 || t == hl - 1) return true;
    float c = s[t];
    return (c >= s[t - 1]) && (c >= s[t + 1]);
  };
  int cnt = 0;
  for (int t = lo; t < hi; ++t) cnt += flag(t) ? 1 : 0;

  // 2-wave exclusive scan of chunk counts
  int lane = tid & 63, wid = tid >> 6;
  int incl = cnt;
#pragma unroll
  for (int off = 1; off < 64; off <<= 1) {
    int v = __shfl_up(incl, off, 64);
    if (lane >= off) incl += v;
  }
  if (lane == 63) wsum[wid] = incl;
  __syncthreads();
  int hn = wsum[0] + wsum[1];
  int excl = ((wid == 1) ? wsum[0] : 0) + incl - cnt;
  for (int t = lo; t < hi; ++t) {
    if (flag(t)) vi[excl++] = (unsigned short)t;
  }
  __syncthreads();

  if (g == 0 && tid == 0) hn_out[b] = (float)hn;
  if (k0 >= M) return;
  int kend = k0 + SEG_P; if (kend > M) kend = M;

  // ---- R5 rolling-atom pool body (score & vi from LDS) ----
  int lane4 = tid;                       // 128 lanes x float4 = D=512
  const float4* fr = (const float4*)(feat + (size_t)b * T * (size_t)D);

  float4 ap = make_float4(0.f, 0.f, 0.f, 0.f);
  float ssp = 0.f;
  if (k0 < hn) {
    int as = (k0 == 0) ? 0 : vi[k0 - 1];
    int ae = vi[k0];
    for (int t = as; t < ae; ++t) {
      float sc = s[t];
      float4 f = fr[(size_t)t * 128 + lane4];
      ap.x += sc * f.x; ap.y += sc * f.y; ap.z += sc * f.z; ap.w += sc * f.w;
      ssp += sc;
    }
  }

  for (int k = k0; k < kend; ++k) {
    float4* o4 = (float4*)(out + ((size_t)b * M + k) * D);
    if (k >= hn) {
      o4[lane4] = make_float4(0.f, 0.f, 0.f, 0.f);
      continue;
    }
    if (k == hn - 1) {
      float inv = 1.f / (ssp + 1e-10f);
      o4[lane4] = make_float4(ap.x * inv, ap.y * inv, ap.z * inv, ap.w * inv);
      ssp = 0.f; ap = make_float4(0.f, 0.f, 0.f, 0.f);
      continue;
    }
    float4 ac = make_float4(0.f, 0.f, 0.f, 0.f);
    float ssc = 0.f;
    int as = vi[k];
    int ae = vi[k + 1];
    for (int t = as; t < ae; ++t) {
      float sc = s[t];
      float4 f = fr[(size_t)t * 128 + lane4];
      ac.x += sc * f.x; ac.y += sc * f.y; ac.z += sc * f.z; ac.w += sc * f.w;
      ssc += sc;
    }
    float inv = 1.f / (ssp + ssc + 1e-10f);
    o4[lane4] = make_float4((ap.x + ac.x) * inv, (ap.y + ac.y) * inv,
                            (ap.z + ac.z) * inv, (ap.w + ac.w) * inv);
    ap = ac; ssp = ssc;
  }
}

extern "C" void kernel_launch(void* const* d_in, const int* in_sizes, int n_in,
                              void* d_out, int out_size, void* d_ws, size_t ws_size,
                              hipStream_t stream) {
  const float* feat = (const float*)d_in[0];
  const float* W    = (const float*)d_in[1];
  const float* bias = (const float*)d_in[2];
  const int* hlens  = (const int*)d_in[3];

  int D = in_sizes[1];                 // 512
  int B = in_sizes[3];                 // 16
  int T = in_sizes[0] / (B * D);       // 2000
  int M = (out_size - B - B * T) / (B * D);  // data-dependent max segments

  float* out      = (float*)d_out;
  float* hn_out   = out + (size_t)B * M * D;      // [B] (as float)
  float* score    = hn_out + B;                   // [B, T]

  int nrows = B * T;
  score_kernel<<<(nrows + 3) / 4, 256, 0, stream>>>(feat, W, bias, score, nrows, D);

  int ngrp = (M + SEG_P - 1) / SEG_P;
  segpool_kernel<<<B * ngrp, 128, 0, stream>>>(feat, score, hlens, out, hn_out,
                                               T, D, M, ngrp);
}

// Round 12
// 34.398 us; speedup vs baseline: 1.4237x; 1.4237x over previous
//
#include <hip/hip_runtime.h>
#include <math.h>

#define MAX_T 2048
#define SEG_P 4   // segments per pool block (measured optimum: {1:40.6, 2:37.5, 4:35.3, 8:~39} µs)

typedef float f32x4 __attribute__((ext_vector_type(4)));  // native vec for NT stores

// ---------------- Kernel 1: score = sigmoid(feat . W + b) ----------------
// One wave (64 lanes) per (b,t) row. float4 coalesced loads.
__global__ void score_kernel(const float* __restrict__ feat,
                             const float* __restrict__ W,
                             const float* __restrict__ bias,
                             float* __restrict__ score,
                             int nrows, int D) {
  int row = blockIdx.x * 4 + (threadIdx.x >> 6);
  int lane = threadIdx.x & 63;
  if (row >= nrows) return;
  const float4* f4 = (const float4*)(feat + (size_t)row * D);
  const float4* w4 = (const float4*)W;
  float acc = 0.f;
  int n4 = D >> 2;
  for (int idx = lane; idx < n4; idx += 64) {
    float4 a = f4[idx];
    float4 w = w4[idx];
    acc += a.x * w.x + a.y * w.y + a.z * w.z + a.w * w.w;
  }
#pragma unroll
  for (int off = 32; off > 0; off >>= 1) acc += __shfl_xor(acc, off, 64);
  if (lane == 0) {
    float x = acc + bias[0];
    score[row] = 1.f / (1.f + expf(-x));
  }
}

// ---------------- Kernel 2: valley detect -> vi table (1024 thr) --------
// One block per batch element. vi[j] = frame index of valley j.
// Atom j := [vi[j-1], vi[j]) with vi[-1]:=0 (atom 0 empty since vi[0]==0).
// Segment k = atom k U atom k+1 (k<hn-1); segment hn-1 = atom hn-1.
__global__ __launch_bounds__(1024) void seg_kernel(
    const float* __restrict__ score, const int* __restrict__ hlens,
    int* __restrict__ vi_ws, int* __restrict__ hn_ws,
    float* __restrict__ hn_out, int T, int M) {
  int b = blockIdx.x;
  int tid = threadIdx.x;
  const int NT = 1024;
  __shared__ float s[MAX_T];
  __shared__ unsigned char fl[MAX_T];
  __shared__ int vi[MAX_T];
  __shared__ int wsum[16];

  const float* sr = score + (size_t)b * T;
  int hl = hlens[b];

  for (int t = tid; t < T; t += NT) s[t] = sr[t];
  __syncthreads();

  for (int t = tid; t < T; t += NT) {
    bool f;
    if (t >= hl)                     f = false;
    else if (t == 0 || t == hl - 1)  f = true;
    else {
      float c = s[t];
      f = (c >= s[t - 1]) && (c >= s[t + 1]);
    }
    fl[t] = f ? (unsigned char)1 : (unsigned char)0;
  }
  __syncthreads();

  int C = (T + NT - 1) / NT;            // 2
  int lo = tid * C;
  int hi = lo + C; if (hi > T) hi = T; if (lo > T) lo = T;
  int cnt = 0;
  for (int t = lo; t < hi; ++t) cnt += fl[t];

  int lane = tid & 63, wid = tid >> 6;  // 16 waves
  int incl = cnt;
#pragma unroll
  for (int off = 1; off < 64; off <<= 1) {
    int v = __shfl_up(incl, off, 64);
    if (lane >= off) incl += v;
  }
  if (lane == 63) wsum[wid] = incl;
  __syncthreads();
  int wofs = 0, hn = 0;
#pragma unroll
  for (int w = 0; w < 16; ++w) {
    if (w < wid) wofs += wsum[w];
    hn += wsum[w];
  }
  int excl = wofs + incl - cnt;
  for (int t = lo; t < hi; ++t) {
    if (fl[t]) vi[excl++] = t;
  }
  __syncthreads();

  for (int j = tid; j < M; j += NT) {
    vi_ws[(size_t)b * M + j] = (j < hn) ? vi[j] : 0;
  }
  if (tid == 0) {
    hn_ws[b] = hn;
    hn_out[b] = (float)hn;
  }
}

// ---------------- Kernel 3: grouped rolling-atom pool (R5 body) ---------
// One 128-thread block per SEG_P consecutive segments of one batch.
// Rolling 2-atom register window; feat read 1.25x, served mostly from L3.
// Output stores are nontemporal (write-once; keep caches for feat).
__global__ __launch_bounds__(128) void pool_kernel(
    const float* __restrict__ feat, const float* __restrict__ score,
    const int* __restrict__ vi_ws, const int* __restrict__ hn_ws,
    float* __restrict__ out, int T, int D, int M, int ngrp) {
  int gid = blockIdx.x;
  int lane = threadIdx.x;                 // 128 lanes, float4 covers D=512
  int b = gid / ngrp;
  int g = gid - b * ngrp;
  int k0 = g * SEG_P;
  if (k0 >= M) return;

  int hn = hn_ws[b];
  const int* vi = vi_ws + (size_t)b * M;
  const float* sr = score + (size_t)b * T;
  const float4* fr = (const float4*)(feat + (size_t)b * T * (size_t)D);

  int kend = k0 + SEG_P; if (kend > M) kend = M;

  auto store_nt = [&](int k, float x, float y, float z, float w) {
    f32x4 r; r.x = x; r.y = y; r.z = z; r.w = w;
    __builtin_nontemporal_store(r, (f32x4*)(out + ((size_t)b * M + k) * D) + lane);
  };

  float4 ap = make_float4(0.f, 0.f, 0.f, 0.f);
  float ssp = 0.f;
  if (k0 < hn) {
    int as = (k0 == 0) ? 0 : vi[k0 - 1];
    int ae = vi[k0];
    for (int t = as; t < ae; ++t) {
      float sc = sr[t];
      float4 f = fr[(size_t)t * 128 + lane];
      ap.x += sc * f.x; ap.y += sc * f.y; ap.z += sc * f.z; ap.w += sc * f.w;
      ssp += sc;
    }
  }

  for (int k = k0; k < kend; ++k) {
    if (k >= hn) {
      store_nt(k, 0.f, 0.f, 0.f, 0.f);
      continue;
    }
    if (k == hn - 1) {
      float inv = 1.f / (ssp + 1e-10f);
      store_nt(k, ap.x * inv, ap.y * inv, ap.z * inv, ap.w * inv);
      ssp = 0.f; ap = make_float4(0.f, 0.f, 0.f, 0.f);
      continue;
    }
    float4 ac = make_float4(0.f, 0.f, 0.f, 0.f);
    float ssc = 0.f;
    int as = vi[k];
    int ae = vi[k + 1];
    for (int t = as; t < ae; ++t) {
      float sc = sr[t];
      float4 f = fr[(size_t)t * 128 + lane];
      ac.x += sc * f.x; ac.y += sc * f.y; ac.z += sc * f.z; ac.w += sc * f.w;
      ssc += sc;
    }
    float inv = 1.f / (ssp + ssc + 1e-10f);
    store_nt(k, (ap.x + ac.x) * inv, (ap.y + ac.y) * inv,
             (ap.z + ac.z) * inv, (ap.w + ac.w) * inv);
    ap = ac; ssp = ssc;
  }
}

extern "C" void kernel_launch(void* const* d_in, const int* in_sizes, int n_in,
                              void* d_out, int out_size, void* d_ws, size_t ws_size,
                              hipStream_t stream) {
  const float* feat = (const float*)d_in[0];
  const float* W    = (const float*)d_in[1];
  const float* bias = (const float*)d_in[2];
  const int* hlens  = (const int*)d_in[3];

  int D = in_sizes[1];                 // 512
  int B = in_sizes[3];                 // 16
  int T = in_sizes[0] / (B * D);       // 2000
  int M = (out_size - B - B * T) / (B * D);  // data-dependent max segments

  float* out      = (float*)d_out;
  float* hn_out   = out + (size_t)B * M * D;      // [B] (as float)
  float* score    = hn_out + B;                   // [B, T]

  // ws layout: vi[B*M] int | hn_ws[B] int
  int* vi_ws = (int*)d_ws;
  int* hn_ws = vi_ws + (size_t)B * M;

  int nrows = B * T;
  score_kernel<<<(nrows + 3) / 4, 256, 0, stream>>>(feat, W, bias, score, nrows, D);
  seg_kernel<<<B, 1024, 0, stream>>>(score, hlens, vi_ws, hn_ws, hn_out, T, M);

  int ngrp = (M + SEG_P - 1) / SEG_P;
  pool_kernel<<<B * ngrp, 128, 0, stream>>>(feat, score, vi_ws, hn_ws,
                                            out, T, D, M, ngrp);
}